// Round 1
// baseline (398.264 us; speedup 1.0000x reference)
//
#include <hip/hip_runtime.h>

// ---------------------------------------------------------------------------
// HybridLossDynamic: total = mse + ssim_loss + 0.7*gme over (2,1,128,128,128)
// fp32 volumes. Outputs: [total, mse, ssim_loss, gme].
//
// Pipeline (all on `stream`, ws layout below):
//   k_init        : zero bin accumulators, min=+inf / max=0
//   k_wblur_mse   : W-blur of {p,t,p2,t2,pt} -> A[5] (80 MiB in ws), + MSE reduce
//   k_hdblur_ssim : fused H+D blur per tile (LDS) + SSIM map + reduce
//   k_sobel       : 9x Sobel 3x3x3 w/ reflect pad -> gm volumes (reuse A space),
//                   + per-volume min/max (binned atomics)
//   k_edge_diff   : |norm_p - norm_t| reduce
//   k_final       : fold bins, write 4 outputs
//
// ws usage: 5*VOL*4 = 83,886,080 B for A, + 28,672 B accumulators.
// ---------------------------------------------------------------------------

#define VOL 4194304        // 2*128^3 elements per field (batch folded in)

// 11-tap Gaussian, sigma=1.5, normalized (computed in double, rounded):
constexpr float GW[11] = {
    0.00102838f, 0.00759876f, 0.03600077f, 0.10936070f, 0.21300554f,
    0.26601173f,
    0.21300554f, 0.10936070f, 0.03600077f, 0.00759876f, 0.00102838f};

// 9 Sobel kernels, [filter][z*9+y*3+x], correlation (no flip) — matches
// jax.lax.conv_general_dilated semantics. n1=1,n2=2,n3*n2=4.
constexpr float SOB[9][27] = {
    // Sx
    {-1,0,1,-2,0,2,-1,0,1,  -2,0,2,-4,0,4,-2,0,2,  -1,0,1,-2,0,2,-1,0,1},
    // Sy
    {-1,-2,-1,0,0,0,1,2,1,  -2,-4,-2,0,0,0,2,4,2,  -1,-2,-1,0,0,0,1,2,1},
    // Sz
    {-1,-2,-1,-2,-4,-2,-1,-2,-1,  0,0,0,0,0,0,0,0,0,  1,2,1,2,4,2,1,2,1},
    // Sd11
    {0,1,2,-1,0,1,-2,-1,0,  0,2,4,-2,0,2,-4,-2,0,  0,1,2,-1,0,1,-2,-1,0},
    // Sd12
    {-2,-1,0,-1,0,1,0,1,2,  -4,-2,0,-2,0,2,0,2,4,  -2,-1,0,-1,0,1,0,1,2},
    // Sd21 = Sd11.T (axes reversed)
    {0,0,0,-1,-2,-1,-2,-4,-2,  1,2,1,0,0,0,-1,-2,-1,  2,4,2,1,2,1,0,0,0},
    // Sd22 = Sd12.T
    {-2,-4,-2,-1,-2,-1,0,0,0,  -1,-2,-1,0,0,0,1,2,1,  0,0,0,1,2,1,2,4,2},
    // Sd31[i][b][c] = -Sd11[b][c][i]
    {0,1,2,0,2,4,0,1,2,  -1,0,1,-2,0,2,-1,0,1,  -2,-1,0,-4,-2,0,-2,-1,0},
    // Sd32[i][b][c] =  Sd12[b][c][i]
    {-2,-1,0,-4,-2,0,-2,-1,0,  -1,0,1,-2,0,2,-1,0,1,  0,1,2,0,2,4,0,1,2}};

// Accumulator region layout (doubles first, then uints):
//   dbl[0..511]     mse bins    (64 bins, stride 8 doubles = 64B)
//   dbl[512..1023]  ssim bins
//   dbl[1024..1535] abs bins
//   ui[0..1023]     min bins vol0 (stride 16 uints = 64B)
//   ui[1024..2047]  min bins vol1
//   ui[2048..3071]  max bins vol0
//   ui[3072..4095]  max bins vol1

__global__ __launch_bounds__(256) void k_init(double* dbl, unsigned int* ui) {
  const int tid = threadIdx.x + (blockIdx.x << 8);
  if (tid < 1536) dbl[tid] = 0.0;
  if (tid < 4096) ui[tid] = (tid < 2048) ? 0x7F800000u : 0u;
}

// ---- K1: blur along W (contiguous) for 5 fields + MSE partial --------------
__global__ __launch_bounds__(256) void k_wblur_mse(
    const float* __restrict__ p, const float* __restrict__ t,
    float* __restrict__ A, double* __restrict__ mseB) {
  __shared__ float pr[2][138];
  __shared__ float tr[2][138];
  __shared__ float red[256];
  const int tid = threadIdx.x;
  const int rl = tid >> 7;   // which of the 2 rows this thread serves
  const int x  = tid & 127;
  float msel = 0.f;
  for (int it = 0; it < 8; ++it) {           // 16 rows per block
    const int row  = (blockIdx.x << 4) + (it << 1) + rl;
    const int base = row << 7;
    const float pv = p[base + x];
    const float tv = t[base + x];
    pr[rl][5 + x] = pv; tr[rl][5 + x] = tv;
    if (x < 5)    { pr[rl][x] = 0.f;      tr[rl][x] = 0.f; }
    if (x >= 123) { pr[rl][10 + x] = 0.f; tr[rl][10 + x] = 0.f; }
    __syncthreads();
    float ap = 0.f, at = 0.f, app = 0.f, att = 0.f, apt = 0.f;
#pragma unroll
    for (int k = 0; k < 11; ++k) {
      const float w = GW[k];
      const float a = pr[rl][x + k];
      const float b = tr[rl][x + k];
      ap += w * a; at += w * b;
      app += w * a * a; att += w * b * b; apt += w * a * b;
    }
    const int idx = base + x;
    A[idx]           = ap;
    A[VOL + idx]     = at;
    A[2 * VOL + idx] = app;
    A[3 * VOL + idx] = att;
    A[4 * VOL + idx] = apt;
    const float d = pv - tv;
    msel += d * d;
    __syncthreads();                         // LDS reuse next iter
  }
  red[tid] = msel;
  __syncthreads();
  for (int s = 128; s > 0; s >>= 1) {
    if (tid < s) red[tid] += red[tid + s];
    __syncthreads();
  }
  if (tid == 0) atomicAdd(&mseB[(blockIdx.x & 63) << 3], (double)red[0]);
}

// ---- K2: fused H+D blur per tile + SSIM map + reduce -----------------------
// tile: 16(z) x 8(y) x 8(x) outputs; halo region 26 x 18 x 8.
__global__ __launch_bounds__(256) void k_hdblur_ssim(
    const float* __restrict__ A, double* __restrict__ ssimB) {
  __shared__ float s_in[3744];   // 26*18*8, x stride 1, y stride 8, z stride 144
  __shared__ float s_h[1664];    // 26*8*8,  x 1, y 8, z 64
  __shared__ float s_out[5120];  // 5 * 1024
  const int tid = threadIdx.x;
  const int x0 = blockIdx.x << 3;
  const int y0 = blockIdx.y << 3;
  const int b  = blockIdx.z >> 3;
  const int z0 = (blockIdx.z & 7) << 4;
  const int vb = b << 21;
  for (int q = 0; q < 5; ++q) {
    const float* __restrict__ Aq = A + q * VOL + vb;
    for (int l = tid; l < 3744; l += 256) {
      const int lx = l & 7;
      const int ly = (l >> 3) % 18;
      const int lz = l / 144;
      const int gz = z0 - 5 + lz;
      const int gy = y0 - 5 + ly;
      float v = 0.f;
      if ((unsigned)gz < 128u && (unsigned)gy < 128u)
        v = Aq[(((gz << 7) + gy) << 7) + x0 + lx];
      s_in[l] = v;
    }
    __syncthreads();
    for (int l = tid; l < 1664; l += 256) {     // H blur
      const int lx = l & 7;
      const int ly = (l >> 3) & 7;
      const int lz = l >> 6;
      const float* sp = &s_in[lz * 144 + (ly << 3) + lx];
      float a = 0.f;
#pragma unroll
      for (int k = 0; k < 11; ++k) a += GW[k] * sp[k << 3];
      s_h[l] = a;
    }
    __syncthreads();
    for (int l = tid; l < 1024; l += 256) {     // D blur (s_h idx = l + k*64)
      float a = 0.f;
#pragma unroll
      for (int k = 0; k < 11; ++k) a += GW[k] * s_h[l + (k << 6)];
      s_out[(q << 10) + l] = a;
    }
    __syncthreads();
  }
  float lsum = 0.f;
#pragma unroll
  for (int i = 0; i < 4; ++i) {
    const int l = tid + (i << 8);
    const float mp  = s_out[l];
    const float mt  = s_out[1024 + l];
    const float epp = s_out[2048 + l];
    const float ett = s_out[3072 + l];
    const float ept = s_out[4096 + l];
    const float mp2 = mp * mp, mt2 = mt * mt, mpt = mp * mt;
    const float num = (2.f * mpt + 1e-4f) * (2.f * (ept - mpt) + 9e-4f);
    const float den = (mp2 + mt2 + 1e-4f) * ((epp - mp2) + (ett - mt2) + 9e-4f);
    lsum += num / den;
  }
  __syncthreads();
  s_in[tid] = lsum;
  __syncthreads();
  for (int s = 128; s > 0; s >>= 1) {
    if (tid < s) s_in[tid] += s_in[tid + s];
    __syncthreads();
  }
  if (tid == 0) {
    const int bin = (blockIdx.x + (blockIdx.y << 4) + (blockIdx.z << 8)) & 63;
    atomicAdd(&ssimB[bin << 3], (double)s_in[0]);
  }
}

// ---- E1: Sobel gradient magnitude + per-volume min/max ---------------------
// tile: 8(z) x 8(y) x 16(x); region 10 x 10 x 18 (reflect-padded, always valid)
__global__ __launch_bounds__(256) void k_sobel(
    const float* __restrict__ p, const float* __restrict__ t,
    float* __restrict__ gmP, float* __restrict__ gmT,
    unsigned int* __restrict__ ui) {
  __shared__ float s[1800];
  __shared__ float rmin[256];
  __shared__ float rmax[256];
  const int tid = threadIdx.x;
  const int x0 = blockIdx.x << 4;
  const int y0 = blockIdx.y << 3;
  const int vol = blockIdx.z >> 5;
  const int b   = (blockIdx.z >> 4) & 1;
  const int z0  = (blockIdx.z & 15) << 3;
  const float* __restrict__ img = vol ? t : p;
  float* __restrict__ gm = vol ? gmT : gmP;
  const int vb = b << 21;
  for (int l = tid; l < 1800; l += 256) {
    const int lx = l % 18;
    const int ly = (l / 18) % 10;
    const int lz = l / 180;
    int gz = z0 - 1 + lz; gz = (gz < 0) ? 1 : ((gz > 127) ? 126 : gz);
    int gy = y0 - 1 + ly; gy = (gy < 0) ? 1 : ((gy > 127) ? 126 : gy);
    int gx = x0 - 1 + lx; gx = (gx < 0) ? 1 : ((gx > 127) ? 126 : gx);
    s[l] = img[vb + (((gz << 7) + gy) << 7) + gx];
  }
  __syncthreads();
  float lmin = 3.4e38f, lmax = 0.f;
#pragma unroll
  for (int i = 0; i < 4; ++i) {
    const int l  = tid + (i << 8);
    const int lx = l & 15;
    const int ly = (l >> 4) & 7;
    const int lz = l >> 7;
    float v[27];
#pragma unroll
    for (int dz = 0; dz < 3; ++dz)
#pragma unroll
      for (int dy = 0; dy < 3; ++dy)
#pragma unroll
        for (int dx = 0; dx < 3; ++dx)
          v[(dz * 3 + dy) * 3 + dx] =
              s[(lz + dz) * 180 + (ly + dy) * 18 + (lx + dx)];
    float ssum = 0.f;
#pragma unroll
    for (int c = 0; c < 9; ++c) {
      float g = 0.f;
#pragma unroll
      for (int j = 0; j < 27; ++j) g += SOB[c][j] * v[j];
      g += 1e-6f;
      ssum += g * g;
    }
    const float gv = sqrtf(ssum + 9e-6f);
    gm[vb + ((((z0 + lz) << 7) + (y0 + ly)) << 7) + (x0 + lx)] = gv;
    lmin = fminf(lmin, gv);
    lmax = fmaxf(lmax, gv);
  }
  rmin[tid] = lmin; rmax[tid] = lmax;
  __syncthreads();
  for (int st = 128; st > 0; st >>= 1) {
    if (tid < st) {
      rmin[tid] = fminf(rmin[tid], rmin[tid + st]);
      rmax[tid] = fmaxf(rmax[tid], rmax[tid + st]);
    }
    __syncthreads();
  }
  if (tid == 0) {
    const int bin = (blockIdx.x + (blockIdx.y << 3) + (blockIdx.z << 7)) & 63;
    atomicMin(&ui[vol * 1024 + (bin << 4)], __float_as_uint(rmin[0]));
    atomicMax(&ui[2048 + vol * 1024 + (bin << 4)], __float_as_uint(rmax[0]));
  }
}

// ---- E2: mean |norm_p - norm_t| --------------------------------------------
__global__ __launch_bounds__(256) void k_edge_diff(
    const float* __restrict__ gmP, const float* __restrict__ gmT,
    const unsigned int* __restrict__ ui, double* __restrict__ absB) {
  float mnp = 3.4e38f, mnt = 3.4e38f, mxp = 0.f, mxt = 0.f;
  for (int j = 0; j < 64; ++j) {
    mnp = fminf(mnp, __uint_as_float(ui[j << 4]));
    mnt = fminf(mnt, __uint_as_float(ui[1024 + (j << 4)]));
    mxp = fmaxf(mxp, __uint_as_float(ui[2048 + (j << 4)]));
    mxt = fmaxf(mxt, __uint_as_float(ui[3072 + (j << 4)]));
  }
  const float scp = 1.f / (mxp - mnp + 1e-6f);
  const float sct = 1.f / (mxt - mnt + 1e-6f);
  float lsum = 0.f;
  const int base = blockIdx.x << 10;
#pragma unroll
  for (int i = 0; i < 4; ++i) {
    const int idx = base + (i << 8) + threadIdx.x;
    const float a = (gmP[idx] - mnp) * scp;
    const float b = (gmT[idx] - mnt) * sct;
    lsum += fabsf(a - b);
  }
  __shared__ float red[256];
  red[threadIdx.x] = lsum;
  __syncthreads();
  for (int s = 128; s > 0; s >>= 1) {
    if (threadIdx.x < s) red[threadIdx.x] += red[threadIdx.x + s];
    __syncthreads();
  }
  if (threadIdx.x == 0)
    atomicAdd(&absB[(blockIdx.x & 63) << 3], (double)red[0]);
}

// ---- final: fold bins, emit the 4 scalars ----------------------------------
__global__ void k_final(const double* __restrict__ dbl, float* __restrict__ out) {
  if (threadIdx.x == 0 && blockIdx.x == 0) {
    double ms = 0.0, ss = 0.0, ab = 0.0;
    for (int j = 0; j < 64; ++j) {
      ms += dbl[j << 3];
      ss += dbl[512 + (j << 3)];
      ab += dbl[1024 + (j << 3)];
    }
    const double N = 4194304.0;
    const double mse   = ms / N;
    const double ssiml = 1.0 - ss / N;
    const double gme   = 1e-6 + ab / N;
    const double total = mse + ssiml + 0.7 * gme;
    out[0] = (float)total;
    out[1] = (float)mse;
    out[2] = (float)ssiml;
    out[3] = (float)gme;
  }
}

extern "C" void kernel_launch(void* const* d_in, const int* in_sizes, int n_in,
                              void* d_out, int out_size, void* d_ws, size_t ws_size,
                              hipStream_t stream) {
  const float* p = (const float*)d_in[0];
  const float* t = (const float*)d_in[1];
  float* A = (float*)d_ws;
  char* accb = (char*)d_ws + (size_t)5 * VOL * 4;   // 83,886,080
  double* dbl = (double*)accb;
  unsigned int* ui = (unsigned int*)(accb + 12288);
  float* out = (float*)d_out;
  float* gmP = A;           // reuse A space after k_hdblur_ssim consumed it
  float* gmT = A + VOL;

  k_init<<<16, 256, 0, stream>>>(dbl, ui);
  k_wblur_mse<<<2048, 256, 0, stream>>>(p, t, A, dbl);
  k_hdblur_ssim<<<dim3(16, 16, 16), 256, 0, stream>>>(A, dbl + 512);
  k_sobel<<<dim3(8, 16, 64), 256, 0, stream>>>(p, t, gmP, gmT, ui);
  k_edge_diff<<<4096, 256, 0, stream>>>(gmP, gmT, ui, dbl + 1024);
  k_final<<<1, 64, 0, stream>>>(dbl, out);
}

// Round 2
// 275.868 us; speedup vs baseline: 1.4437x; 1.4437x over previous
//
#include <hip/hip_runtime.h>

// ---------------------------------------------------------------------------
// HybridLossDynamic: total = mse + ssim_loss + 0.7*gme over (2,1,128,128,128)
// fp32 volumes. Outputs: [total, mse, ssim_loss, gme].
//
// Pipeline (all on `stream`):
//   k_init          : zero bin accumulators, min=+inf / max=0
//   per batch b in {0,1}:                       (keeps ws at 80 MiB + 28 KB)
//     k_wblur_mse   : W-blur of {p,t,p2,t2,pt} -> A[5xHV] + MSE reduce
//     k_blur_y      : y-blur A -> B, register-ring streaming (no LDS)
//     k_zblur_ssim  : z-blur B (5 simultaneous rings) + SSIM map + reduce
//   k_sobel         : 9x Sobel 3x3x3 w/ reflect pad -> gm volumes (reuse ws),
//                     + per-volume min/max (binned atomics)
//   k_edge_diff     : |norm_p - norm_t| reduce
//   k_final         : fold bins, write 4 outputs
//
// ws layout: [0,5*HV) A | [5*HV,10*HV) B | 80MiB: accumulators (28,672 B)
// gm volumes reuse [0, 2*VOL) after SSIM passes are done.
// ---------------------------------------------------------------------------

#define VOL 4194304        // 2*128^3 (both batch images)
#define HV  2097152        // one batch image, 128^3

// 11-tap Gaussian, sigma=1.5, normalized:
constexpr float GW[11] = {
    0.00102838f, 0.00759876f, 0.03600077f, 0.10936070f, 0.21300554f,
    0.26601173f,
    0.21300554f, 0.10936070f, 0.03600077f, 0.00759876f, 0.00102838f};

// 9 Sobel kernels, [filter][z*9+y*3+x], correlation order.
constexpr float SOB[9][27] = {
    {-1,0,1,-2,0,2,-1,0,1,  -2,0,2,-4,0,4,-2,0,2,  -1,0,1,-2,0,2,-1,0,1},
    {-1,-2,-1,0,0,0,1,2,1,  -2,-4,-2,0,0,0,2,4,2,  -1,-2,-1,0,0,0,1,2,1},
    {-1,-2,-1,-2,-4,-2,-1,-2,-1,  0,0,0,0,0,0,0,0,0,  1,2,1,2,4,2,1,2,1},
    {0,1,2,-1,0,1,-2,-1,0,  0,2,4,-2,0,2,-4,-2,0,  0,1,2,-1,0,1,-2,-1,0},
    {-2,-1,0,-1,0,1,0,1,2,  -4,-2,0,-2,0,2,0,2,4,  -2,-1,0,-1,0,1,0,1,2},
    {0,0,0,-1,-2,-1,-2,-4,-2,  1,2,1,0,0,0,-1,-2,-1,  2,4,2,1,2,1,0,0,0},
    {-2,-4,-2,-1,-2,-1,0,0,0,  -1,-2,-1,0,0,0,1,2,1,  0,0,0,1,2,1,2,4,2},
    {0,1,2,0,2,4,0,1,2,  -1,0,1,-2,0,2,-1,0,1,  -2,-1,0,-4,-2,0,-2,-1,0},
    {-2,-1,0,-4,-2,0,-2,-1,0,  -1,0,1,-2,0,2,-1,0,1,  0,1,2,0,2,4,0,1,2}};

// Accumulator region layout:
//   dbl[0..511] mse bins | dbl[512..1023] ssim bins | dbl[1024..1535] abs bins
//   ui[0..1023] min v0 | ui[1024..2047] min v1 | ui[2048..3071] max v0 |
//   ui[3072..4095] max v1   (64 bins, 64B stride)

__global__ __launch_bounds__(256) void k_init(double* dbl, unsigned int* ui) {
  const int tid = threadIdx.x + (blockIdx.x << 8);
  if (tid < 1536) dbl[tid] = 0.0;
  if (tid < 4096) ui[tid] = (tid < 2048) ? 0x7F800000u : 0u;
}

// ---- K1: blur along W (contiguous) for 5 fields + MSE partial (per batch) --
__global__ __launch_bounds__(256) void k_wblur_mse(
    const float* __restrict__ p, const float* __restrict__ t,
    float* __restrict__ A, double* __restrict__ mseB) {
  __shared__ float pr[2][138];
  __shared__ float tr[2][138];
  __shared__ float red[256];
  const int tid = threadIdx.x;
  const int rl = tid >> 7;
  const int x  = tid & 127;
  float msel = 0.f;
  for (int it = 0; it < 8; ++it) {           // 16 rows per block
    const int row  = (blockIdx.x << 4) + (it << 1) + rl;
    const int base = row << 7;
    const float pv = p[base + x];
    const float tv = t[base + x];
    pr[rl][5 + x] = pv; tr[rl][5 + x] = tv;
    if (x < 5)    { pr[rl][x] = 0.f;      tr[rl][x] = 0.f; }
    if (x >= 123) { pr[rl][10 + x] = 0.f; tr[rl][10 + x] = 0.f; }
    __syncthreads();
    float ap = 0.f, at = 0.f, app = 0.f, att = 0.f, apt = 0.f;
#pragma unroll
    for (int k = 0; k < 11; ++k) {
      const float w = GW[k];
      const float a = pr[rl][x + k];
      const float b = tr[rl][x + k];
      ap += w * a; at += w * b;
      app += w * a * a; att += w * b * b; apt += w * a * b;
    }
    const int idx = base + x;
    A[idx]          = ap;
    A[HV + idx]     = at;
    A[2 * HV + idx] = app;
    A[3 * HV + idx] = att;
    A[4 * HV + idx] = apt;
    const float d = pv - tv;
    msel += d * d;
    __syncthreads();
  }
  red[tid] = msel;
  __syncthreads();
  for (int s = 128; s > 0; s >>= 1) {
    if (tid < s) red[tid] += red[tid + s];
    __syncthreads();
  }
  if (tid == 0) atomicAdd(&mseB[(blockIdx.x & 63) << 3], (double)red[0]);
}

// ---- K2a: y-blur A -> B, register ring, fully coalesced, no LDS ------------
// thread: fixed (x,z), streams 16 y outputs. grid dim3(64, 8).
__global__ __launch_bounds__(256) void k_blur_y(
    const float* __restrict__ A, float* __restrict__ B) {
  const int tid = threadIdx.x;
  const int x = tid & 127;
  const int z = (blockIdx.x << 1) + (tid >> 7);
  const int y0 = blockIdx.y << 4;
  const int col = (z << 14) + x;
  for (int q = 0; q < 5; ++q) {
    const float* __restrict__ Aq = A + q * HV + col;
    float* __restrict__ Bq = B + q * HV + col;
    float win[11];
#pragma unroll
    for (int k = 0; k < 10; ++k) {
      const int y = y0 - 5 + k;
      win[k] = ((unsigned)y < 128u) ? Aq[y << 7] : 0.f;
    }
#pragma unroll
    for (int i = 0; i < 16; ++i) {
      const int y = y0 + i;
      win[10] = (y + 5 < 128) ? Aq[(y + 5) << 7] : 0.f;
      float a = 0.f;
#pragma unroll
      for (int k = 0; k < 11; ++k) a += GW[k] * win[k];
      Bq[y << 7] = a;
#pragma unroll
      for (int k = 0; k < 10; ++k) win[k] = win[k + 1];
    }
  }
}

// ---- K2b: z-blur B (5 rings) + SSIM map + reduce ---------------------------
// thread: fixed (x,y), streams 16 z outputs. grid dim3(64, 8).
__global__ __launch_bounds__(256) void k_zblur_ssim(
    const float* __restrict__ B, double* __restrict__ ssimB) {
  const int tid = threadIdx.x;
  const int x = tid & 127;
  const int y = (blockIdx.x << 1) + (tid >> 7);
  const int z0 = blockIdx.y << 4;
  const int col = (y << 7) + x;
  float win[5][11];
#pragma unroll
  for (int q = 0; q < 5; ++q) {
    const float* __restrict__ Bq = B + q * HV + col;
#pragma unroll
    for (int k = 0; k < 10; ++k) {
      const int z = z0 - 5 + k;
      win[q][k] = ((unsigned)z < 128u) ? Bq[z << 14] : 0.f;
    }
  }
  float lsum = 0.f;
#pragma unroll
  for (int i = 0; i < 16; ++i) {
    const int zl = z0 + i + 5;
    float m[5];
#pragma unroll
    for (int q = 0; q < 5; ++q) {
      win[q][10] = (zl < 128) ? B[q * HV + col + (zl << 14)] : 0.f;
      float a = 0.f;
#pragma unroll
      for (int k = 0; k < 11; ++k) a += GW[k] * win[q][k];
      m[q] = a;
#pragma unroll
      for (int k = 0; k < 10; ++k) win[q][k] = win[q][k + 1];
    }
    const float mp = m[0], mt = m[1], epp = m[2], ett = m[3], ept = m[4];
    const float mp2 = mp * mp, mt2 = mt * mt, mpt = mp * mt;
    const float num = (2.f * mpt + 1e-4f) * (2.f * (ept - mpt) + 9e-4f);
    const float den = (mp2 + mt2 + 1e-4f) * ((epp - mp2) + (ett - mt2) + 9e-4f);
    lsum += num / den;
  }
  __shared__ float red[256];
  red[tid] = lsum;
  __syncthreads();
  for (int s = 128; s > 0; s >>= 1) {
    if (tid < s) red[tid] += red[tid + s];
    __syncthreads();
  }
  if (tid == 0) {
    const int bin = (blockIdx.x + (blockIdx.y << 6)) & 63;
    atomicAdd(&ssimB[bin << 3], (double)red[0]);
  }
}

// ---- E1: Sobel gradient magnitude + per-volume min/max ---------------------
__global__ __launch_bounds__(256) void k_sobel(
    const float* __restrict__ p, const float* __restrict__ t,
    float* __restrict__ gmP, float* __restrict__ gmT,
    unsigned int* __restrict__ ui) {
  __shared__ float s[1800];
  __shared__ float rmin[256];
  __shared__ float rmax[256];
  const int tid = threadIdx.x;
  const int x0 = blockIdx.x << 4;
  const int y0 = blockIdx.y << 3;
  const int vol = blockIdx.z >> 5;
  const int b   = (blockIdx.z >> 4) & 1;
  const int z0  = (blockIdx.z & 15) << 3;
  const float* __restrict__ img = vol ? t : p;
  float* __restrict__ gm = vol ? gmT : gmP;
  const int vb = b << 21;
  for (int l = tid; l < 1800; l += 256) {
    const int lx = l % 18;
    const int ly = (l / 18) % 10;
    const int lz = l / 180;
    int gz = z0 - 1 + lz; gz = (gz < 0) ? 1 : ((gz > 127) ? 126 : gz);
    int gy = y0 - 1 + ly; gy = (gy < 0) ? 1 : ((gy > 127) ? 126 : gy);
    int gx = x0 - 1 + lx; gx = (gx < 0) ? 1 : ((gx > 127) ? 126 : gx);
    s[l] = img[vb + (((gz << 7) + gy) << 7) + gx];
  }
  __syncthreads();
  float lmin = 3.4e38f, lmax = 0.f;
#pragma unroll
  for (int i = 0; i < 4; ++i) {
    const int l  = tid + (i << 8);
    const int lx = l & 15;
    const int ly = (l >> 4) & 7;
    const int lz = l >> 7;
    float v[27];
#pragma unroll
    for (int dz = 0; dz < 3; ++dz)
#pragma unroll
      for (int dy = 0; dy < 3; ++dy)
#pragma unroll
        for (int dx = 0; dx < 3; ++dx)
          v[(dz * 3 + dy) * 3 + dx] =
              s[(lz + dz) * 180 + (ly + dy) * 18 + (lx + dx)];
    float ssum = 0.f;
#pragma unroll
    for (int c = 0; c < 9; ++c) {
      float g = 0.f;
#pragma unroll
      for (int j = 0; j < 27; ++j) g += SOB[c][j] * v[j];
      g += 1e-6f;
      ssum += g * g;
    }
    const float gv = sqrtf(ssum + 9e-6f);
    gm[vb + ((((z0 + lz) << 7) + (y0 + ly)) << 7) + (x0 + lx)] = gv;
    lmin = fminf(lmin, gv);
    lmax = fmaxf(lmax, gv);
  }
  rmin[tid] = lmin; rmax[tid] = lmax;
  __syncthreads();
  for (int st = 128; st > 0; st >>= 1) {
    if (tid < st) {
      rmin[tid] = fminf(rmin[tid], rmin[tid + st]);
      rmax[tid] = fmaxf(rmax[tid], rmax[tid + st]);
    }
    __syncthreads();
  }
  if (tid == 0) {
    const int bin = (blockIdx.x + (blockIdx.y << 3) + (blockIdx.z << 7)) & 63;
    atomicMin(&ui[vol * 1024 + (bin << 4)], __float_as_uint(rmin[0]));
    atomicMax(&ui[2048 + vol * 1024 + (bin << 4)], __float_as_uint(rmax[0]));
  }
}

// ---- E2: mean |norm_p - norm_t| --------------------------------------------
__global__ __launch_bounds__(256) void k_edge_diff(
    const float* __restrict__ gmP, const float* __restrict__ gmT,
    const unsigned int* __restrict__ ui, double* __restrict__ absB) {
  float mnp = 3.4e38f, mnt = 3.4e38f, mxp = 0.f, mxt = 0.f;
  for (int j = 0; j < 64; ++j) {
    mnp = fminf(mnp, __uint_as_float(ui[j << 4]));
    mnt = fminf(mnt, __uint_as_float(ui[1024 + (j << 4)]));
    mxp = fmaxf(mxp, __uint_as_float(ui[2048 + (j << 4)]));
    mxt = fmaxf(mxt, __uint_as_float(ui[3072 + (j << 4)]));
  }
  const float scp = 1.f / (mxp - mnp + 1e-6f);
  const float sct = 1.f / (mxt - mnt + 1e-6f);
  float lsum = 0.f;
  const int base = blockIdx.x << 10;
#pragma unroll
  for (int i = 0; i < 4; ++i) {
    const int idx = base + (i << 8) + threadIdx.x;
    const float a = (gmP[idx] - mnp) * scp;
    const float b = (gmT[idx] - mnt) * sct;
    lsum += fabsf(a - b);
  }
  __shared__ float red[256];
  red[threadIdx.x] = lsum;
  __syncthreads();
  for (int s = 128; s > 0; s >>= 1) {
    if (threadIdx.x < s) red[threadIdx.x] += red[threadIdx.x + s];
    __syncthreads();
  }
  if (threadIdx.x == 0)
    atomicAdd(&absB[(blockIdx.x & 63) << 3], (double)red[0]);
}

// ---- final: fold bins, emit the 4 scalars ----------------------------------
__global__ void k_final(const double* __restrict__ dbl, float* __restrict__ out) {
  if (threadIdx.x == 0 && blockIdx.x == 0) {
    double ms = 0.0, ss = 0.0, ab = 0.0;
    for (int j = 0; j < 64; ++j) {
      ms += dbl[j << 3];
      ss += dbl[512 + (j << 3)];
      ab += dbl[1024 + (j << 3)];
    }
    const double N = 4194304.0;
    const double mse   = ms / N;
    const double ssiml = 1.0 - ss / N;
    const double gme   = 1e-6 + ab / N;
    const double total = mse + ssiml + 0.7 * gme;
    out[0] = (float)total;
    out[1] = (float)mse;
    out[2] = (float)ssiml;
    out[3] = (float)gme;
  }
}

extern "C" void kernel_launch(void* const* d_in, const int* in_sizes, int n_in,
                              void* d_out, int out_size, void* d_ws, size_t ws_size,
                              hipStream_t stream) {
  const float* p = (const float*)d_in[0];
  const float* t = (const float*)d_in[1];
  float* A = (float*)d_ws;                          // 5*HV floats (40 MiB)
  float* B = A + (size_t)5 * HV;                    // 5*HV floats (40 MiB)
  char* accb = (char*)d_ws + (size_t)10 * HV * 4;   // 83,886,080
  double* dbl = (double*)accb;
  unsigned int* ui = (unsigned int*)(accb + 12288);
  float* out = (float*)d_out;
  float* gmP = (float*)d_ws;        // reuse A/B space after SSIM done
  float* gmT = gmP + VOL;

  k_init<<<16, 256, 0, stream>>>(dbl, ui);
  for (int b = 0; b < 2; ++b) {
    k_wblur_mse<<<1024, 256, 0, stream>>>(p + (size_t)b * HV, t + (size_t)b * HV,
                                          A, dbl);
    k_blur_y<<<dim3(64, 8), 256, 0, stream>>>(A, B);
    k_zblur_ssim<<<dim3(64, 8), 256, 0, stream>>>(B, dbl + 512);
  }
  k_sobel<<<dim3(8, 16, 64), 256, 0, stream>>>(p, t, gmP, gmT, ui);
  k_edge_diff<<<4096, 256, 0, stream>>>(gmP, gmT, ui, dbl + 1024);
  k_final<<<1, 64, 0, stream>>>(dbl, out);
}

// Round 3
// 234.204 us; speedup vs baseline: 1.7005x; 1.1779x over previous
//
#include <hip/hip_runtime.h>

// ---------------------------------------------------------------------------
// HybridLossDynamic: total = mse + ssim_loss + 0.7*gme over (2,1,128,128,128)
// fp32 volumes. Outputs: [total, mse, ssim_loss, gme].
//
// Pipeline (all on `stream`):
//   k_init          : zero bin accumulators, min=+inf / max=0
//   per batch b in {0,1}:
//     k_wblur_mse   : W-blur of {p,t,p2,t2,pt} -> A[5xHV] + MSE reduce
//     k_blur_y      : y-blur A -> B, register-ring streaming (no LDS)
//     k_zblur_ssim  : z-blur B (5 simultaneous rings) + SSIM map + reduce
//   k_sobel         : separable Sobel (s/d/u tensor decomposition),
//                     z-streamed, triple-buffered slice LDS, min/max atomics
//   k_edge_diff     : |norm_p - norm_t| reduce
//   k_final         : fold bins, write 4 outputs
//
// ws layout: [0,5*HV) A | [5*HV,10*HV) B | 80MiB: accumulators (28,672 B)
// gm volumes reuse [0, 2*VOL) after SSIM passes are done.
// ---------------------------------------------------------------------------

#define VOL 4194304        // 2*128^3 (both batch images)
#define HV  2097152        // one batch image, 128^3

// 11-tap Gaussian, sigma=1.5, normalized:
constexpr float GW[11] = {
    0.00102838f, 0.00759876f, 0.03600077f, 0.10936070f, 0.21300554f,
    0.26601173f,
    0.21300554f, 0.10936070f, 0.03600077f, 0.00759876f, 0.00102838f};

// Accumulator region layout:
//   dbl[0..511] mse bins | dbl[512..1023] ssim bins | dbl[1024..1535] abs bins
//   ui[0..1023] min v0 | ui[1024..2047] min v1 | ui[2048..3071] max v0 |
//   ui[3072..4095] max v1   (64 bins, 64B stride)

__global__ __launch_bounds__(256) void k_init(double* dbl, unsigned int* ui) {
  const int tid = threadIdx.x + (blockIdx.x << 8);
  if (tid < 1536) dbl[tid] = 0.0;
  if (tid < 4096) ui[tid] = (tid < 2048) ? 0x7F800000u : 0u;
}

// ---- K1: blur along W (contiguous) for 5 fields + MSE partial (per batch) --
__global__ __launch_bounds__(256) void k_wblur_mse(
    const float* __restrict__ p, const float* __restrict__ t,
    float* __restrict__ A, double* __restrict__ mseB) {
  __shared__ float pr[2][138];
  __shared__ float tr[2][138];
  __shared__ float red[256];
  const int tid = threadIdx.x;
  const int rl = tid >> 7;
  const int x  = tid & 127;
  float msel = 0.f;
  for (int it = 0; it < 8; ++it) {           // 16 rows per block
    const int row  = (blockIdx.x << 4) + (it << 1) + rl;
    const int base = row << 7;
    const float pv = p[base + x];
    const float tv = t[base + x];
    pr[rl][5 + x] = pv; tr[rl][5 + x] = tv;
    if (x < 5)    { pr[rl][x] = 0.f;      tr[rl][x] = 0.f; }
    if (x >= 123) { pr[rl][10 + x] = 0.f; tr[rl][10 + x] = 0.f; }
    __syncthreads();
    float ap = 0.f, at = 0.f, app = 0.f, att = 0.f, apt = 0.f;
#pragma unroll
    for (int k = 0; k < 11; ++k) {
      const float w = GW[k];
      const float a = pr[rl][x + k];
      const float b = tr[rl][x + k];
      ap += w * a; at += w * b;
      app += w * a * a; att += w * b * b; apt += w * a * b;
    }
    const int idx = base + x;
    A[idx]          = ap;
    A[HV + idx]     = at;
    A[2 * HV + idx] = app;
    A[3 * HV + idx] = att;
    A[4 * HV + idx] = apt;
    const float d = pv - tv;
    msel += d * d;
    __syncthreads();
  }
  red[tid] = msel;
  __syncthreads();
  for (int s = 128; s > 0; s >>= 1) {
    if (tid < s) red[tid] += red[tid + s];
    __syncthreads();
  }
  if (tid == 0) atomicAdd(&mseB[(blockIdx.x & 63) << 3], (double)red[0]);
}

// ---- K2a: y-blur A -> B, register ring, fully coalesced, no LDS ------------
__global__ __launch_bounds__(256) void k_blur_y(
    const float* __restrict__ A, float* __restrict__ B) {
  const int tid = threadIdx.x;
  const int x = tid & 127;
  const int z = (blockIdx.x << 1) + (tid >> 7);
  const int y0 = blockIdx.y << 4;
  const int col = (z << 14) + x;
  for (int q = 0; q < 5; ++q) {
    const float* __restrict__ Aq = A + q * HV + col;
    float* __restrict__ Bq = B + q * HV + col;
    float win[11];
#pragma unroll
    for (int k = 0; k < 10; ++k) {
      const int y = y0 - 5 + k;
      win[k] = ((unsigned)y < 128u) ? Aq[y << 7] : 0.f;
    }
#pragma unroll
    for (int i = 0; i < 16; ++i) {
      const int y = y0 + i;
      win[10] = (y + 5 < 128) ? Aq[(y + 5) << 7] : 0.f;
      float a = 0.f;
#pragma unroll
      for (int k = 0; k < 11; ++k) a += GW[k] * win[k];
      Bq[y << 7] = a;
#pragma unroll
      for (int k = 0; k < 10; ++k) win[k] = win[k + 1];
    }
  }
}

// ---- K2b: z-blur B (5 rings) + SSIM map + reduce ---------------------------
__global__ __launch_bounds__(256) void k_zblur_ssim(
    const float* __restrict__ B, double* __restrict__ ssimB) {
  const int tid = threadIdx.x;
  const int x = tid & 127;
  const int y = (blockIdx.x << 1) + (tid >> 7);
  const int z0 = blockIdx.y << 4;
  const int col = (y << 7) + x;
  float win[5][11];
#pragma unroll
  for (int q = 0; q < 5; ++q) {
    const float* __restrict__ Bq = B + q * HV + col;
#pragma unroll
    for (int k = 0; k < 10; ++k) {
      const int z = z0 - 5 + k;
      win[q][k] = ((unsigned)z < 128u) ? Bq[z << 14] : 0.f;
    }
  }
  float lsum = 0.f;
#pragma unroll
  for (int i = 0; i < 16; ++i) {
    const int zl = z0 + i + 5;
    float m[5];
#pragma unroll
    for (int q = 0; q < 5; ++q) {
      win[q][10] = (zl < 128) ? B[q * HV + col + (zl << 14)] : 0.f;
      float a = 0.f;
#pragma unroll
      for (int k = 0; k < 11; ++k) a += GW[k] * win[q][k];
      m[q] = a;
#pragma unroll
      for (int k = 0; k < 10; ++k) win[q][k] = win[q][k + 1];
    }
    const float mp = m[0], mt = m[1], epp = m[2], ett = m[3], ept = m[4];
    const float mp2 = mp * mp, mt2 = mt * mt, mpt = mp * mt;
    const float num = (2.f * mpt + 1e-4f) * (2.f * (ept - mpt) + 9e-4f);
    const float den = (mp2 + mt2 + 1e-4f) * ((epp - mp2) + (ett - mt2) + 9e-4f);
    lsum += num / den;
  }
  __shared__ float red[256];
  red[tid] = lsum;
  __syncthreads();
  for (int s = 128; s > 0; s >>= 1) {
    if (tid < s) red[tid] += red[tid + s];
    __syncthreads();
  }
  if (tid == 0) {
    const int bin = (blockIdx.x + (blockIdx.y << 6)) & 63;
    atomicAdd(&ssimB[bin << 3], (double)red[0]);
  }
}

// ---- E1: Sobel via separable s/d/u decomposition, z-streamed ---------------
// All 9 filters decompose over s=[1,2,1], d=[-1,0,1], u=[1,1,1]:
//   g1=Sx=s⊗s⊗d  g2=Sy=s⊗d⊗s  g3=Sz=d⊗s⊗s
//   Sd11/12 = s_z⊗(u_y d_x ∓ d_y u_x) = A∓B ; A=s_z u_y d_x, B=s_z d_y u_x
//   Sd21/22 = (d_z u_y ∓ u_z d_y)⊗s_x = C∓D ; C=d_z u_y s_x, D=u_z d_y s_x
//   Sd31/32 = u_z s_y d_x ∓ d_z s_y u_x    = E∓F
// Per z-slice we compute 7 Y-terms once, reuse for 3 consecutive outputs.
// Block: 16x16 (x,y) tile, 32-z segment; triple-buffered 18x18 slice LDS.
__global__ __launch_bounds__(256) void k_sobel(
    const float* __restrict__ p, const float* __restrict__ t,
    float* __restrict__ gmP, float* __restrict__ gmT,
    unsigned int* __restrict__ ui) {
  __shared__ float sb[972];     // 3 x 18*18 slice buffers
  __shared__ float rmin[256];
  __shared__ float rmax[256];
  const int tid = threadIdx.x;
  const int tx = tid & 15;
  const int ty = tid >> 4;
  const int x0 = blockIdx.x << 4;
  const int y0 = blockIdx.y << 4;
  const int vol = blockIdx.z >> 3;
  const int b   = (blockIdx.z >> 2) & 1;
  const int z0  = (blockIdx.z & 3) << 5;
  const float* __restrict__ img = vol ? t : p;
  float* __restrict__ gm = vol ? gmT : gmP;
  const int vb = b << 21;

  // staging geometry (fixed per thread; reflect clamp on x,y hoisted):
  const int l1 = tid;                       // element 1 of the 18x18 slice
  const int ly1 = l1 / 18, lx1 = l1 % 18;
  int gy1 = y0 - 1 + ly1; gy1 = gy1 < 0 ? 1 : (gy1 > 127 ? 126 : gy1);
  int gx1 = x0 - 1 + lx1; gx1 = gx1 < 0 ? 1 : (gx1 > 127 ? 126 : gx1);
  const int off1 = (gy1 << 7) + gx1;
  const int l2 = tid + 256;                 // element 2 (tid<68 only)
  const int ly2 = l2 / 18, lx2 = l2 % 18;
  int gy2 = y0 - 1 + ly2; gy2 = gy2 < 0 ? 1 : (gy2 > 127 ? 126 : gy2);
  int gx2 = x0 - 1 + lx2; gx2 = gx2 < 0 ? 1 : (gx2 > 127 ? 126 : gx2);
  const int off2 = (gy2 << 7) + gx2;
  const bool has2 = (tid < 68);
  const int rb = ty * 18 + tx;              // read corner in slice frame
  const int gbase = vb + (z0 << 14) + ((y0 + ty) << 7) + (x0 + tx);

  float Y0[7], Y1[7], Y2[7];
  float lmin = 3.4e38f, lmax = 0.f;

#define STAGE(ZS, BOFF) {                                                   \
    const int zc_ = (ZS) > 127 ? 126 : (ZS);                                \
    const int za_ = vb + (zc_ << 14);                                       \
    sb[(BOFF) + l1] = img[za_ + off1];                                      \
    if (has2) sb[(BOFF) + l2] = img[za_ + off2]; }

#define COMPY(P) {                                                          \
    const int o_ = (P) * 324 + rb;                                          \
    const float r00 = sb[o_],      r01 = sb[o_ + 1],  r02 = sb[o_ + 2];     \
    const float r10 = sb[o_ + 18], r11 = sb[o_ + 19], r12 = sb[o_ + 20];    \
    const float r20 = sb[o_ + 36], r21 = sb[o_ + 37], r22 = sb[o_ + 38];    \
    const float dx0 = r02 - r00, dx1 = r12 - r10, dx2 = r22 - r20;          \
    const float ux0 = r00 + r01 + r02, ux1 = r10 + r11 + r12,               \
                ux2 = r20 + r21 + r22;                                      \
    const float sx0 = ux0 + r01, sx1 = ux1 + r11, sx2 = ux2 + r21;          \
    Y##P[1] = dx0 + dx1 + dx2;           /* uydx */                         \
    Y##P[0] = Y##P[1] + dx1;             /* sydx */                         \
    Y##P[2] = sx2 - sx0;                 /* dysx */                         \
    Y##P[4] = sx0 + sx1 + sx2;           /* uysx */                         \
    Y##P[3] = Y##P[4] + sx1;             /* sysx */                         \
    Y##P[5] = ux2 - ux0;                 /* dyux */                         \
    Y##P[6] = (ux0 + ux2) + 2.f * ux1; } /* syux */

#define EMIT(I, P0, P1, P2) {                                               \
    const float E_ = Y##P0[0] + Y##P1[0] + Y##P2[0];                        \
    const float g1 = E_ + Y##P1[0];                                         \
    const float tA = Y##P0[1] + Y##P1[1] + Y##P2[1];                        \
    const float A_ = tA + Y##P1[1];                                         \
    const float D_ = Y##P0[2] + Y##P1[2] + Y##P2[2];                        \
    const float g2 = D_ + Y##P1[2];                                         \
    const float g3 = Y##P2[3] - Y##P0[3];                                   \
    const float C_ = Y##P2[4] - Y##P0[4];                                   \
    const float B_ = (Y##P0[5] + Y##P2[5]) + 2.f * Y##P1[5];                \
    const float F_ = Y##P2[6] - Y##P0[6];                                   \
    const float g4 = A_ - B_, g5 = A_ + B_;                                 \
    const float g6 = C_ - D_, g7 = C_ + D_;                                 \
    const float g8 = E_ - F_, g9 = E_ + F_;                                 \
    float ss_ = 9e-6f, t_;                                                  \
    t_ = g1 + 1e-6f; ss_ = fmaf(t_, t_, ss_);                               \
    t_ = g2 + 1e-6f; ss_ = fmaf(t_, t_, ss_);                               \
    t_ = g3 + 1e-6f; ss_ = fmaf(t_, t_, ss_);                               \
    t_ = g4 + 1e-6f; ss_ = fmaf(t_, t_, ss_);                               \
    t_ = g5 + 1e-6f; ss_ = fmaf(t_, t_, ss_);                               \
    t_ = g6 + 1e-6f; ss_ = fmaf(t_, t_, ss_);                               \
    t_ = g7 + 1e-6f; ss_ = fmaf(t_, t_, ss_);                               \
    t_ = g8 + 1e-6f; ss_ = fmaf(t_, t_, ss_);                               \
    t_ = g9 + 1e-6f; ss_ = fmaf(t_, t_, ss_);                               \
    const float gv = sqrtf(ss_);                                            \
    gm[gbase + ((I) << 14)] = gv;                                           \
    lmin = fminf(lmin, gv); lmax = fmaxf(lmax, gv); }

#define BODY(I, P0, P1, P2) {                                               \
    STAGE(z0 + (I) + 1, (P2) * 324);                                        \
    __syncthreads();                                                        \
    COMPY(P2);                                                              \
    EMIT(I, P0, P1, P2); }

  // prime: slices z0-1 (reflect at z0==0) and z0 into buffers 0,1
  {
    const int zp = (z0 == 0) ? 1 : (z0 - 1);
    STAGE(zp, 0);
    STAGE(z0, 324);
    __syncthreads();
    COMPY(0);
    COMPY(1);
  }
  for (int ii = 0; ii < 30; ii += 3) {
    BODY(ii,     0, 1, 2);
    BODY(ii + 1, 1, 2, 0);
    BODY(ii + 2, 2, 0, 1);
  }
  BODY(30, 0, 1, 2);
  BODY(31, 1, 2, 0);

#undef BODY
#undef EMIT
#undef COMPY
#undef STAGE

  rmin[tid] = lmin; rmax[tid] = lmax;
  __syncthreads();
  for (int st = 128; st > 0; st >>= 1) {
    if (tid < st) {
      rmin[tid] = fminf(rmin[tid], rmin[tid + st]);
      rmax[tid] = fmaxf(rmax[tid], rmax[tid + st]);
    }
    __syncthreads();
  }
  if (tid == 0) {
    const int bin = (blockIdx.x + (blockIdx.y << 3) + (blockIdx.z << 6)) & 63;
    atomicMin(&ui[vol * 1024 + (bin << 4)], __float_as_uint(rmin[0]));
    atomicMax(&ui[2048 + vol * 1024 + (bin << 4)], __float_as_uint(rmax[0]));
  }
}

// ---- E2: mean |norm_p - norm_t| --------------------------------------------
__global__ __launch_bounds__(256) void k_edge_diff(
    const float* __restrict__ gmP, const float* __restrict__ gmT,
    const unsigned int* __restrict__ ui, double* __restrict__ absB) {
  float mnp = 3.4e38f, mnt = 3.4e38f, mxp = 0.f, mxt = 0.f;
  for (int j = 0; j < 64; ++j) {
    mnp = fminf(mnp, __uint_as_float(ui[j << 4]));
    mnt = fminf(mnt, __uint_as_float(ui[1024 + (j << 4)]));
    mxp = fmaxf(mxp, __uint_as_float(ui[2048 + (j << 4)]));
    mxt = fmaxf(mxt, __uint_as_float(ui[3072 + (j << 4)]));
  }
  const float scp = 1.f / (mxp - mnp + 1e-6f);
  const float sct = 1.f / (mxt - mnt + 1e-6f);
  float lsum = 0.f;
  const int base = blockIdx.x << 10;
#pragma unroll
  for (int i = 0; i < 4; ++i) {
    const int idx = base + (i << 8) + threadIdx.x;
    const float a = (gmP[idx] - mnp) * scp;
    const float b = (gmT[idx] - mnt) * sct;
    lsum += fabsf(a - b);
  }
  __shared__ float red[256];
  red[threadIdx.x] = lsum;
  __syncthreads();
  for (int s = 128; s > 0; s >>= 1) {
    if (threadIdx.x < s) red[threadIdx.x] += red[threadIdx.x + s];
    __syncthreads();
  }
  if (threadIdx.x == 0)
    atomicAdd(&absB[(blockIdx.x & 63) << 3], (double)red[0]);
}

// ---- final: fold bins, emit the 4 scalars ----------------------------------
__global__ void k_final(const double* __restrict__ dbl, float* __restrict__ out) {
  if (threadIdx.x == 0 && blockIdx.x == 0) {
    double ms = 0.0, ss = 0.0, ab = 0.0;
    for (int j = 0; j < 64; ++j) {
      ms += dbl[j << 3];
      ss += dbl[512 + (j << 3)];
      ab += dbl[1024 + (j << 3)];
    }
    const double N = 4194304.0;
    const double mse   = ms / N;
    const double ssiml = 1.0 - ss / N;
    const double gme   = 1e-6 + ab / N;
    const double total = mse + ssiml + 0.7 * gme;
    out[0] = (float)total;
    out[1] = (float)mse;
    out[2] = (float)ssiml;
    out[3] = (float)gme;
  }
}

extern "C" void kernel_launch(void* const* d_in, const int* in_sizes, int n_in,
                              void* d_out, int out_size, void* d_ws, size_t ws_size,
                              hipStream_t stream) {
  const float* p = (const float*)d_in[0];
  const float* t = (const float*)d_in[1];
  float* A = (float*)d_ws;                          // 5*HV floats (40 MiB)
  float* B = A + (size_t)5 * HV;                    // 5*HV floats (40 MiB)
  char* accb = (char*)d_ws + (size_t)10 * HV * 4;   // 83,886,080
  double* dbl = (double*)accb;
  unsigned int* ui = (unsigned int*)(accb + 12288);
  float* out = (float*)d_out;
  float* gmP = (float*)d_ws;        // reuse A/B space after SSIM done
  float* gmT = gmP + VOL;

  k_init<<<16, 256, 0, stream>>>(dbl, ui);
  for (int b = 0; b < 2; ++b) {
    k_wblur_mse<<<1024, 256, 0, stream>>>(p + (size_t)b * HV, t + (size_t)b * HV,
                                          A, dbl);
    k_blur_y<<<dim3(64, 8), 256, 0, stream>>>(A, B);
    k_zblur_ssim<<<dim3(64, 8), 256, 0, stream>>>(B, dbl + 512);
  }
  k_sobel<<<dim3(8, 8, 16), 256, 0, stream>>>(p, t, gmP, gmT, ui);
  k_edge_diff<<<4096, 256, 0, stream>>>(gmP, gmT, ui, dbl + 1024);
  k_final<<<1, 64, 0, stream>>>(dbl, out);
}